// Round 3
// baseline (526.518 us; speedup 1.0000x reference)
//
#include <hip/hip_runtime.h>
#include <hip/hip_bf16.h>
#include <math.h>

typedef short short8 __attribute__((ext_vector_type(8)));
typedef float f32x4 __attribute__((ext_vector_type(4)));

#define CC 768
#define NN 1024
#define RR 32768
#define MM 512
#define ZSTRIDE 786432      // C*H*W
#define OUT_ATTN_OFF 25165824

static __device__ __forceinline__ short f2bf(float f) {
    __hip_bfloat16 h = __float2bfloat16(f);
    return *reinterpret_cast<short*>(&h);
}

// async global->LDS DMA, 16B per lane (dst wave-uniform base, HW adds lane*16)
static __device__ __forceinline__ void gl_lds16(const float* g, float* l) {
    __builtin_amdgcn_global_load_lds(
        (const __attribute__((address_space(1))) void*)g,
        (__attribute__((address_space(3))) void*)l, 16, 0, 0);
}

// fast exp for x in [-2.2, +1e-6], f64 accuracy ~1e-14 rel, branch-free
static __device__ __forceinline__ double fast_exp_neg(double x) {
    const double LOG2E = 1.4426950408889634074;
    const double LN2   = 0.6931471805599453094;
    const double MAGIC = 6755399441055744.0;     // 1.5 * 2^52
    double t = x * LOG2E;                         // [-3.2, 0]
    double c = t + MAGIC;
    double n = c - MAGIC;                         // rint(t)
    int ni = (int)__double2loint(c);              // n as int (valid for small |n|)
    double g = (t - n) * LN2;                     // [-0.347, 0.347]
    double r = 2.505210838544172e-08;             // 1/11!
    r = fma(r, g, 2.755731922398589e-07);         // 1/10!
    r = fma(r, g, 2.7557319223985893e-06);        // 1/9!
    r = fma(r, g, 2.48015873015873e-05);          // 1/8!
    r = fma(r, g, 1.984126984126984e-04);         // 1/7!
    r = fma(r, g, 1.388888888888889e-03);         // 1/6!
    r = fma(r, g, 8.333333333333333e-03);         // 1/5!
    r = fma(r, g, 4.1666666666666664e-02);        // 1/4!
    r = fma(r, g, 1.6666666666666666e-01);        // 1/3!
    r = fma(r, g, 0.5);                           // 1/2!
    r = fma(r, g, 1.0);
    r = fma(r, g, 1.0);
    double sc = __hiloint2double((1023 + ni) << 20, 0);   // 2^n
    return r * sc;
}

// f64-accurate reciprocal via f32 seed + 2 Newton steps
static __device__ __forceinline__ double fast_rcp(double x) {
    double r = (double)(1.0f / (float)x);
    r = r * (2.0 - x * r);
    r = r * (2.0 - x * r);
    return r;
}

// ---------------- Kernel A: memory norms + transposed copies ----------------
__global__ __launch_bounds__(256) void prep_mem_kernel(const float* __restrict__ memory,
                                                       float* __restrict__ mem_normT,
                                                       short* __restrict__ memT_bf) {
    int m = blockIdx.x;      // 0..511
    int t = threadIdx.x;
    double ss = 0.0;
    for (int c = t; c < CC; c += 256) {
        float v = memory[m * CC + c];
        ss += (double)v * (double)v;
    }
    #pragma unroll
    for (int off = 32; off > 0; off >>= 1) ss += __shfl_xor(ss, off);
    __shared__ double red[4];
    __shared__ double invs;
    if ((t & 63) == 0) red[t >> 6] = ss;
    __syncthreads();
    if (t == 0) {
        double tot = red[0] + red[1] + red[2] + red[3];
        invs = 1.0 / fmax(sqrt(tot), 1e-12);
    }
    __syncthreads();
    float inv = (float)invs;
    for (int c = t; c < CC; c += 256) {
        float v = memory[m * CC + c];
        mem_normT[c * MM + m] = v * inv;
        memT_bf[c * MM + m]   = f2bf(v);
    }
}

// ---------------- Kernel B: z row inverse norms (f64 accumulate) ----------------
__global__ __launch_bounds__(256) void znorm_kernel(const float* __restrict__ z,
                                                    double* __restrict__ zinv) {
    int row0 = blockIdx.x * 64;
    int b  = row0 >> 10;
    int n0 = row0 & 1023;
    int t  = threadIdx.x;
    int ln = t & 63, cg = t >> 6;
    const float* zb = z + (size_t)b * ZSTRIDE + n0 + ln;
    double ss = 0.0;
    for (int c = cg; c < CC; c += 4) {
        float v = zb[(size_t)c * NN];
        ss += (double)v * (double)v;
    }
    __shared__ double sm[256];
    sm[t] = ss;
    __syncthreads();
    if (t < 64) {
        double tot = sm[t] + sm[t + 64] + sm[t + 128] + sm[t + 192];
        zinv[row0 + t] = 1.0 / fmax(sqrt(tot), 1e-12);
    }
}

// ---------------- Kernel C: f32 scores GEMM + softmax + hardshrink + renorm ----------------
// Block: 32 rows x 512 cols, 256 threads = 4 waves, 4 blocks/CU.
// Wave tr owns rows tr*8..tr*8+7 (8 rows/thread).
// Lane tc owns cols {tc*4+j, 256+tc*4+j : j=0..3}.
__global__ __launch_bounds__(256, 4) void scores_attn_kernel(const float* __restrict__ z,
                                                             const float* __restrict__ mem_normT,
                                                             const double* __restrict__ zinv,
                                                             float* __restrict__ out_attn) {
    __shared__ float zt[2][8][32];       // 2 x 1KB
    __shared__ float bt[2][8][512];      // 2 x 16KB
    int t  = threadIdx.x;
    int tr = t >> 6;                 // wave id 0..3
    int tc = t & 63;                 // lane
    int row0 = blockIdx.x * 32;
    int b  = row0 >> 10;
    int n0 = row0 & 1023;

    const float* zbase = z + (size_t)b * ZSTRIDE + n0;

    float acc[8][8];
    #pragma unroll
    for (int i = 0; i < 8; ++i)
        #pragma unroll
        for (int j = 0; j < 8; ++j) acc[i][j] = 0.f;

    // per-lane source offsets for staging
    int zk = tc >> 3;                    // zt row this lane feeds (wave 0 only)
    int zc = (tc & 7) * 4;               // zt col

    #define STAGE(c0_, bb_)                                                        \
        do {                                                                       \
            if (tr == 0)                                                           \
                gl_lds16(zbase + (size_t)((c0_) + zk) * NN + zc, &zt[bb_][0][0]);  \
            _Pragma("unroll")                                                      \
            for (int q = 0; q < 4; ++q) {                                          \
                int ci = tr * 4 + q;                                               \
                int kb = ci >> 1;                                                  \
                int m  = (ci & 1) * 256 + tc * 4;                                  \
                gl_lds16(mem_normT + (size_t)((c0_) + kb) * MM + m,                \
                         &bt[bb_][0][0] + ci * 256);                               \
            }                                                                      \
        } while (0)

    STAGE(0, 0);
    __syncthreads();

    int cur = 0;
    for (int step = 0; step < CC / 8; ++step) {
        if (step + 1 < CC / 8) STAGE((step + 1) * 8, cur ^ 1);
        #pragma unroll
        for (int kk = 0; kk < 8; ++kk) {
            f32x4 b0 = *reinterpret_cast<const f32x4*>(&bt[cur][kk][tc * 4]);
            f32x4 b1 = *reinterpret_cast<const f32x4*>(&bt[cur][kk][256 + tc * 4]);
            f32x4 a0 = *reinterpret_cast<const f32x4*>(&zt[cur][kk][tr * 8]);
            f32x4 a1 = *reinterpret_cast<const f32x4*>(&zt[cur][kk][tr * 8 + 4]);
            #pragma unroll
            for (int i = 0; i < 8; ++i) {
                float ai = (i < 4) ? a0[i] : a1[i - 4];
                #pragma unroll
                for (int j = 0; j < 8; ++j) {
                    float bj = (j < 4) ? b0[j] : b1[j - 4];
                    acc[i][j] = fmaf(ai, bj, acc[i][j]);
                }
            }
        }
        __syncthreads();   // also drains vmcnt(0): next buffer's DMA complete
        cur ^= 1;
    }
    #undef STAGE

    // ---- epilogue: f64 where additively amplified, f32 elsewhere ----
    #pragma unroll
    for (int i = 0; i < 8; ++i) {
        int row = row0 + tr * 8 + i;
        double zi = zinv[row];
        double s0 = (double)acc[i][0] * zi, s1 = (double)acc[i][1] * zi;
        double s2 = (double)acc[i][2] * zi, s3 = (double)acc[i][3] * zi;
        double s4 = (double)acc[i][4] * zi, s5 = (double)acc[i][5] * zi;
        double s6 = (double)acc[i][6] * zi, s7 = (double)acc[i][7] * zi;
        // shift value: any wave-uniform value works (softmax shift-invariant) -> f32 reduce
        float mf = fmaxf(fmaxf(fmaxf((float)s0, (float)s1), fmaxf((float)s2, (float)s3)),
                         fmaxf(fmaxf((float)s4, (float)s5), fmaxf((float)s6, (float)s7)));
        #pragma unroll
        for (int off = 32; off > 0; off >>= 1) mf = fmaxf(mf, __shfl_xor(mf, off));
        double mx = (double)mf;
        double p0 = fast_exp_neg(s0 - mx), p1 = fast_exp_neg(s1 - mx);
        double p2 = fast_exp_neg(s2 - mx), p3 = fast_exp_neg(s3 - mx);
        double p4 = fast_exp_neg(s4 - mx), p5 = fast_exp_neg(s5 - mx);
        double p6 = fast_exp_neg(s6 - mx), p7 = fast_exp_neg(s7 - mx);
        double Z = ((p0 + p1) + (p2 + p3)) + ((p4 + p5) + (p6 + p7));
        #pragma unroll
        for (int off = 32; off > 0; off >>= 1) Z += __shfl_xor(Z, off);
        double iZ = fast_rcp(Z);
        const double lam = 1.0 / 512.0;
        double w0 = p0 * iZ, w1 = p1 * iZ, w2 = p2 * iZ, w3 = p3 * iZ;
        double w4 = p4 * iZ, w5 = p5 * iZ, w6 = p6 * iZ, w7 = p7 * iZ;
        double d0 = w0 - lam, d1 = w1 - lam, d2 = w2 - lam, d3 = w3 - lam;
        double d4 = w4 - lam, d5 = w5 - lam, d6 = w6 - lam, d7 = w7 - lam;
        // reciprocal here only contributes RELATIVE error (not ramp-amplified) -> f32 ok
        double e0 = (d0 > 0.0 ? d0 : 0.0) * w0 * (double)(1.0f / (float)(fabs(d0) + 1e-8));
        double e1 = (d1 > 0.0 ? d1 : 0.0) * w1 * (double)(1.0f / (float)(fabs(d1) + 1e-8));
        double e2 = (d2 > 0.0 ? d2 : 0.0) * w2 * (double)(1.0f / (float)(fabs(d2) + 1e-8));
        double e3 = (d3 > 0.0 ? d3 : 0.0) * w3 * (double)(1.0f / (float)(fabs(d3) + 1e-8));
        double e4 = (d4 > 0.0 ? d4 : 0.0) * w4 * (double)(1.0f / (float)(fabs(d4) + 1e-8));
        double e5 = (d5 > 0.0 ? d5 : 0.0) * w5 * (double)(1.0f / (float)(fabs(d5) + 1e-8));
        double e6 = (d6 > 0.0 ? d6 : 0.0) * w6 * (double)(1.0f / (float)(fabs(d6) + 1e-8));
        double e7 = (d7 > 0.0 ? d7 : 0.0) * w7 * (double)(1.0f / (float)(fabs(d7) + 1e-8));
        double S = ((e0 + e1) + (e2 + e3)) + ((e4 + e5) + (e6 + e7));
        #pragma unroll
        for (int off = 32; off > 0; off >>= 1) S += __shfl_xor(S, off);
        double rinv = (double)(1.0f / (float)(S + 1e-8));
        f32x4 o0 = { (float)(e0 * rinv), (float)(e1 * rinv),
                     (float)(e2 * rinv), (float)(e3 * rinv) };
        f32x4 o1 = { (float)(e4 * rinv), (float)(e5 * rinv),
                     (float)(e6 * rinv), (float)(e7 * rinv) };
        *reinterpret_cast<f32x4*>(&out_attn[(size_t)row * MM + tc * 4])       = o0;
        *reinterpret_cast<f32x4*>(&out_attn[(size_t)row * MM + 256 + tc * 4]) = o1;
    }
}

// ---------------- Kernel D: z_hat = attn @ memory via bf16 MFMA ----------------
__global__ __launch_bounds__(256) void readout_kernel(const short* __restrict__ memT_bf,
                                                      const float* __restrict__ attn,
                                                      float* __restrict__ out) {
    __shared__ short At[64][40];    // 64 c-rows x 32 k, padded
    __shared__ short Bt[128][40];   // 128 n-rows x 32 k
    int t = threadIdx.x;
    int c0     = blockIdx.x * 64;
    int rowblk = blockIdx.y * 128;
    int b  = rowblk >> 10;
    int nb = rowblk & 1023;
    int lane = t & 63, wv = t >> 6;

    f32x4 acc[4][2];
    #pragma unroll
    for (int fc = 0; fc < 4; ++fc)
        #pragma unroll
        for (int fn = 0; fn < 2; ++fn) acc[fc][fn] = (f32x4){0.f, 0.f, 0.f, 0.f};

    for (int m0 = 0; m0 < MM; m0 += 32) {
        __syncthreads();
        {   // stage A: 64 x 32 bf16
            int r = t >> 2, ko = (t & 3) * 8;
            short8 v = *reinterpret_cast<const short8*>(&memT_bf[(c0 + r) * MM + m0 + ko]);
            *reinterpret_cast<short8*>(&At[r][ko]) = v;
        }
        {   // stage B: 128 x 32, converting attn f32 -> bf16
            int r = t >> 1, ko = (t & 1) * 16;
            const float* src = &attn[(size_t)(rowblk + r) * MM + m0 + ko];
            #pragma unroll
            for (int q = 0; q < 16; ++q) Bt[r][ko + q] = f2bf(src[q]);
        }
        __syncthreads();
        short8 af[4], bfr[2];
        #pragma unroll
        for (int fc = 0; fc < 4; ++fc)
            af[fc] = *reinterpret_cast<const short8*>(&At[fc * 16 + (lane & 15)][(lane >> 4) * 8]);
        #pragma unroll
        for (int fn = 0; fn < 2; ++fn)
            bfr[fn] = *reinterpret_cast<const short8*>(&Bt[wv * 32 + fn * 16 + (lane & 15)][(lane >> 4) * 8]);
        #pragma unroll
        for (int fc = 0; fc < 4; ++fc)
            #pragma unroll
            for (int fn = 0; fn < 2; ++fn)
                acc[fc][fn] = __builtin_amdgcn_mfma_f32_16x16x32_bf16(af[fc], bfr[fn], acc[fc][fn], 0, 0, 0);
    }

    int cg = lane >> 4, cl = lane & 15;
    #pragma unroll
    for (int fc = 0; fc < 4; ++fc)
        #pragma unroll
        for (int fn = 0; fn < 2; ++fn)
            #pragma unroll
            for (int reg = 0; reg < 4; ++reg) {
                int c = c0 + fc * 16 + cg * 4 + reg;
                int n = nb + wv * 32 + fn * 16 + cl;
                out[(size_t)b * ZSTRIDE + (size_t)c * NN + n] = acc[fc][fn][reg];
            }
}

extern "C" void kernel_launch(void* const* d_in, const int* in_sizes, int n_in,
                              void* d_out, int out_size, void* d_ws, size_t ws_size,
                              hipStream_t stream) {
    const float* z      = (const float*)d_in[0];
    const float* memory = (const float*)d_in[1];
    float* out      = (float*)d_out;
    float* out_attn = out + OUT_ATTN_OFF;

    char* wsb = (char*)d_ws;
    float*  mem_normT = (float*)wsb;                  // 768*512*4  = 1572864 B
    short*  memT_bf   = (short*)(wsb + 1572864);      // 768*512*2  =  786432 B
    double* zinv      = (double*)(wsb + 2359296);     // 32768*8    =  262144 B

    prep_mem_kernel<<<512, 256, 0, stream>>>(memory, mem_normT, memT_bf);
    znorm_kernel<<<RR / 64, 256, 0, stream>>>(z, zinv);
    scores_attn_kernel<<<RR / 32, 256, 0, stream>>>(z, mem_normT, zinv, out_attn);
    readout_kernel<<<dim3(CC / 64, RR / 128), 256, 0, stream>>>(memT_bf, out_attn, out);
}

// Round 5
// 401.611 us; speedup vs baseline: 1.3110x; 1.3110x over previous
//
#include <hip/hip_runtime.h>
#include <hip/hip_bf16.h>
#include <math.h>

typedef short short8 __attribute__((ext_vector_type(8)));
typedef float f32x4 __attribute__((ext_vector_type(4)));

#define CC 768
#define NN 1024
#define RR 32768
#define MM 512
#define ZSTRIDE 786432      // C*H*W
#define OUT_ATTN_OFF 25165824

static __device__ __forceinline__ short f2bf(float f) {
    __hip_bfloat16 h = __float2bfloat16(f);
    return *reinterpret_cast<short*>(&h);
}
static __device__ __forceinline__ float bf2f(short s) {
    __hip_bfloat16 h = *reinterpret_cast<__hip_bfloat16*>(&s);
    return __bfloat162float(h);
}

// fast exp for x in [-2.5, +1e-6], f64 accuracy ~1e-14 rel, branch-free
static __device__ __forceinline__ double fast_exp_neg(double x) {
    const double LOG2E = 1.4426950408889634074;
    const double LN2   = 0.6931471805599453094;
    const double MAGIC = 6755399441055744.0;     // 1.5 * 2^52
    double t = x * LOG2E;
    double c = t + MAGIC;
    double n = c - MAGIC;                         // rint(t)
    int ni = (int)__double2loint(c);              // n as int (small |n|)
    double g = (t - n) * LN2;                     // [-0.347, 0.347]
    double r = 2.505210838544172e-08;             // 1/11!
    r = fma(r, g, 2.755731922398589e-07);
    r = fma(r, g, 2.7557319223985893e-06);
    r = fma(r, g, 2.48015873015873e-05);
    r = fma(r, g, 1.984126984126984e-04);
    r = fma(r, g, 1.388888888888889e-03);
    r = fma(r, g, 8.333333333333333e-03);
    r = fma(r, g, 4.1666666666666664e-02);
    r = fma(r, g, 1.6666666666666666e-01);
    r = fma(r, g, 0.5);
    r = fma(r, g, 1.0);
    r = fma(r, g, 1.0);
    double sc = __hiloint2double((1023 + ni) << 20, 0);   // 2^n
    return r * sc;
}

// f64-accurate reciprocal via f32 seed + 2 Newton steps
static __device__ __forceinline__ double fast_rcp(double x) {
    double r = (double)(1.0f / (float)x);
    r = r * (2.0 - x * r);
    r = r * (2.0 - x * r);
    return r;
}

// ---------------- Kernel A: memory norms + 3-way hi/mid/lo split + raw transpose ----------
__global__ __launch_bounds__(256) void prep_mem_kernel(const float* __restrict__ memory,
                                                       short* __restrict__ mem_h,
                                                       short* __restrict__ mem_m,
                                                       short* __restrict__ mem_l,
                                                       short* __restrict__ memT_bf) {
    int m = blockIdx.x;      // 0..511
    int t = threadIdx.x;
    double ss = 0.0;
    for (int c = t; c < CC; c += 256) {
        float v = memory[m * CC + c];
        ss += (double)v * (double)v;
    }
    #pragma unroll
    for (int off = 32; off > 0; off >>= 1) ss += __shfl_xor(ss, off);
    __shared__ double red[4];
    __shared__ double invs;
    if ((t & 63) == 0) red[t >> 6] = ss;
    __syncthreads();
    if (t == 0) {
        double tot = red[0] + red[1] + red[2] + red[3];
        invs = 1.0 / fmax(sqrt(tot), 1e-12);
    }
    __syncthreads();
    float inv = (float)invs;
    for (int c = t; c < CC; c += 256) {
        float v  = memory[m * CC + c];
        float nv = v * inv;
        short h  = f2bf(nv);
        float r1 = nv - bf2f(h);
        short md = f2bf(r1);
        short l  = f2bf(r1 - bf2f(md));
        mem_h[m * CC + c] = h;
        mem_m[m * CC + c] = md;
        mem_l[m * CC + c] = l;
        memT_bf[c * MM + m] = f2bf(v);
    }
}

// ---------------- Kernel B: scores via 3-way split-bf16 MFMA (6 products) + f64 epilogue --
// Block: 64 z-rows x all 512 memory slots. 256 threads = 4 waves.
// acc[fc][fn]: D row = fc*16 + (lane>>4)*4 + reg, D col = wv*128 + fn*16 + (lane&15).
__global__ __launch_bounds__(256) void scores_attn_kernel(const float* __restrict__ z,
                                                          const short* __restrict__ mem_h,
                                                          const short* __restrict__ mem_m,
                                                          const short* __restrict__ mem_l,
                                                          float* __restrict__ out_attn) {
    __shared__ short AT[2][3][64][40];   // [buf][split][row][k padded] = 30 KB
    __shared__ double redd[4][64];
    __shared__ double ssred[256];
    __shared__ double zld[64];
    __shared__ double mxd[64];
    __shared__ double iZd[64];
    __shared__ double rsd[64];

    const int t    = threadIdx.x;
    const int lane = t & 63;
    const int wv   = t >> 6;
    const int lrow = lane & 15;
    const int gk   = lane >> 4;
    const int row0 = blockIdx.x * 64;
    const int b    = row0 >> 10;
    const int n0   = row0 & 1023;
    const float* zbase = z + (size_t)b * ZSTRIDE + n0 + lane;

    double ss = 0.0;
    f32x4 acc[4][8];
    #pragma unroll
    for (int fc = 0; fc < 4; ++fc)
        #pragma unroll
        for (int fn = 0; fn < 8; ++fn)
            acc[fc][fn] = (f32x4){0.f, 0.f, 0.f, 0.f};

    #define STAGE(bb_, kt_)                                                   \
        do {                                                                  \
            float v_[8];                                                      \
            _Pragma("unroll")                                                 \
            for (int j_ = 0; j_ < 8; ++j_) {                                  \
                v_[j_] = zbase[(size_t)((kt_) * 32 + wv * 8 + j_) * NN];      \
                ss = fma((double)v_[j_], (double)v_[j_], ss);                 \
            }                                                                 \
            short8 h8_, m8_, l8_;                                             \
            _Pragma("unroll")                                                 \
            for (int j_ = 0; j_ < 8; ++j_) {                                  \
                short h_ = f2bf(v_[j_]);                                      \
                float r1_ = v_[j_] - bf2f(h_);                                \
                short md_ = f2bf(r1_);                                        \
                h8_[j_] = h_;                                                 \
                m8_[j_] = md_;                                                \
                l8_[j_] = f2bf(r1_ - bf2f(md_));                              \
            }                                                                 \
            *reinterpret_cast<short8*>(&AT[bb_][0][lane][wv * 8]) = h8_;      \
            *reinterpret_cast<short8*>(&AT[bb_][1][lane][wv * 8]) = m8_;      \
            *reinterpret_cast<short8*>(&AT[bb_][2][lane][wv * 8]) = l8_;      \
        } while (0)

    #define KBODY(cur_, kt_, dostage_)                                        \
        do {                                                                  \
            if (dostage_) STAGE(1 - (cur_), (kt_) + 1);                       \
            short8 ah_[4], am_[4], al_[4];                                    \
            _Pragma("unroll")                                                 \
            for (int fc = 0; fc < 4; ++fc) {                                  \
                ah_[fc] = *reinterpret_cast<const short8*>(                   \
                    &AT[cur_][0][fc * 16 + lrow][gk * 8]);                    \
                am_[fc] = *reinterpret_cast<const short8*>(                   \
                    &AT[cur_][1][fc * 16 + lrow][gk * 8]);                    \
                al_[fc] = *reinterpret_cast<const short8*>(                   \
                    &AT[cur_][2][fc * 16 + lrow][gk * 8]);                    \
            }                                                                 \
            _Pragma("unroll")                                                 \
            for (int fn = 0; fn < 8; ++fn) {                                  \
                const size_t moff = (size_t)(wv * 128 + fn * 16 + lrow) * CC  \
                                    + (size_t)(kt_) * 32 + gk * 8;            \
                short8 bh_ = *reinterpret_cast<const short8*>(mem_h + moff);  \
                short8 bm_ = *reinterpret_cast<const short8*>(mem_m + moff);  \
                short8 bl_ = *reinterpret_cast<const short8*>(mem_l + moff);  \
                _Pragma("unroll")                                             \
                for (int fc = 0; fc < 4; ++fc) {                              \
                    acc[fc][fn] = __builtin_amdgcn_mfma_f32_16x16x32_bf16(    \
                        ah_[fc], bh_, acc[fc][fn], 0, 0, 0);                  \
                    acc[fc][fn] = __builtin_amdgcn_mfma_f32_16x16x32_bf16(    \
                        ah_[fc], bm_, acc[fc][fn], 0, 0, 0);                  \
                    acc[fc][fn] = __builtin_amdgcn_mfma_f32_16x16x32_bf16(    \
                        am_[fc], bh_, acc[fc][fn], 0, 0, 0);                  \
                    acc[fc][fn] = __builtin_amdgcn_mfma_f32_16x16x32_bf16(    \
                        ah_[fc], bl_, acc[fc][fn], 0, 0, 0);                  \
                    acc[fc][fn] = __builtin_amdgcn_mfma_f32_16x16x32_bf16(    \
                        am_[fc], bm_, acc[fc][fn], 0, 0, 0);                  \
                    acc[fc][fn] = __builtin_amdgcn_mfma_f32_16x16x32_bf16(    \
                        al_[fc], bh_, acc[fc][fn], 0, 0, 0);                  \
                }                                                             \
            }                                                                 \
            __syncthreads();                                                  \
        } while (0)

    STAGE(0, 0);
    __syncthreads();
    #pragma unroll 1
    for (int kt = 0; kt < 24; kt += 2) {
        KBODY(0, kt, 1);
        KBODY(1, kt + 1, (kt + 2 < 24));
    }
    #undef KBODY
    #undef STAGE

    // row inverse norms (f64 partials accumulated during staging)
    ssred[t] = ss;
    __syncthreads();
    if (t < 64) {
        double tot = ssred[t] + ssred[t + 64] + ssred[t + 128] + ssred[t + 192];
        zld[t] = 1.0 / fmax(sqrt(tot), 1e-12);
    }
    __syncthreads();

    // ---- P1: raw row max (f32 reduce; scale-commutes since zinv > 0) ----
    #pragma unroll
    for (int fc = 0; fc < 4; ++fc)
        #pragma unroll
        for (int rg = 0; rg < 4; ++rg) {
            float m_ = acc[fc][0][rg];
            #pragma unroll
            for (int fn = 1; fn < 8; ++fn) m_ = fmaxf(m_, acc[fc][fn][rg]);
            #pragma unroll
            for (int off = 1; off < 16; off <<= 1) m_ = fmaxf(m_, __shfl_xor(m_, off));
            if (lrow == 0) redd[wv][fc * 16 + gk * 4 + rg] = (double)m_;
        }
    __syncthreads();
    if (t < 64) {
        double mr = fmax(fmax(redd[0][t], redd[1][t]), fmax(redd[2][t], redd[3][t]));
        mxd[t] = mr * zld[t];
    }
    __syncthreads();

    // ---- P2: Z (f64) ----
    #pragma unroll
    for (int fc = 0; fc < 4; ++fc)
        #pragma unroll
        for (int rg = 0; rg < 4; ++rg) {
            int rl = fc * 16 + gk * 4 + rg;
            double zi = zld[rl], mx = mxd[rl];
            double zp = 0.0;
            #pragma unroll
            for (int fn = 0; fn < 8; ++fn)
                zp += fast_exp_neg((double)acc[fc][fn][rg] * zi - mx);
            #pragma unroll
            for (int off = 1; off < 16; off <<= 1) zp += __shfl_xor(zp, off);
            if (lrow == 0) redd[wv][rl] = zp;
        }
    __syncthreads();
    if (t < 64) {
        double Z = (redd[0][t] + redd[1][t]) + (redd[2][t] + redd[3][t]);
        iZd[t] = fast_rcp(Z);
    }
    __syncthreads();

    // ---- P3: hard-shrink (f64) + renorm sum ----
    const double LAM = 1.0 / 512.0;
    #pragma unroll
    for (int fc = 0; fc < 4; ++fc)
        #pragma unroll
        for (int rg = 0; rg < 4; ++rg) {
            int rl = fc * 16 + gk * 4 + rg;
            double zi = zld[rl], mx = mxd[rl], iZ = iZd[rl];
            double sp = 0.0;
            #pragma unroll
            for (int fn = 0; fn < 8; ++fn) {
                double p = fast_exp_neg((double)acc[fc][fn][rg] * zi - mx);
                double w = p * iZ;
                double d = w - LAM;
                double e = (d > 0.0 ? d : 0.0) * w * fast_rcp(fabs(d) + 1e-8);
                acc[fc][fn][rg] = (float)e;   // post-ramp: relative error only
                sp += e;
            }
            #pragma unroll
            for (int off = 1; off < 16; off <<= 1) sp += __shfl_xor(sp, off);
            if (lrow == 0) redd[wv][rl] = sp;
        }
    __syncthreads();
    if (t < 64) {
        double S = (redd[0][t] + redd[1][t]) + (redd[2][t] + redd[3][t]) + 1e-8;
        rsd[t] = fast_rcp(S);
    }
    __syncthreads();

    // ---- P4: store attn ----
    #pragma unroll
    for (int fc = 0; fc < 4; ++fc)
        #pragma unroll
        for (int rg = 0; rg < 4; ++rg) {
            int rl = fc * 16 + gk * 4 + rg;
            double rv = rsd[rl];
            size_t base = (size_t)(row0 + rl) * MM + wv * 128 + lrow;
            #pragma unroll
            for (int fn = 0; fn < 8; ++fn)
                out_attn[base + fn * 16] = (float)((double)acc[fc][fn][rg] * rv);
        }
}

// ---------------- Kernel C: z_hat = attn @ memory via bf16 MFMA ----------------
__global__ __launch_bounds__(256) void readout_kernel(const short* __restrict__ memT_bf,
                                                      const float* __restrict__ attn,
                                                      float* __restrict__ out) {
    __shared__ short At[64][40];    // 64 c-rows x 32 k, padded
    __shared__ short Bt[128][40];   // 128 n-rows x 32 k
    int t = threadIdx.x;
    int c0     = blockIdx.x * 64;
    int rowblk = blockIdx.y * 128;
    int b  = rowblk >> 10;
    int nb = rowblk & 1023;
    int lane = t & 63, wv = t >> 6;

    f32x4 acc[4][2];
    #pragma unroll
    for (int fc = 0; fc < 4; ++fc)
        #pragma unroll
        for (int fn = 0; fn < 2; ++fn) acc[fc][fn] = (f32x4){0.f, 0.f, 0.f, 0.f};

    for (int m0 = 0; m0 < MM; m0 += 32) {
        __syncthreads();
        {   // stage A: 64 x 32 bf16
            int r = t >> 2, ko = (t & 3) * 8;
            short8 v = *reinterpret_cast<const short8*>(&memT_bf[(c0 + r) * MM + m0 + ko]);
            *reinterpret_cast<short8*>(&At[r][ko]) = v;
        }
        {   // stage B: 128 x 32, attn f32 -> bf16, vectorized
            int r = t >> 1, ko = (t & 1) * 16;
            const f32x4* src = reinterpret_cast<const f32x4*>(
                &attn[(size_t)(rowblk + r) * MM + m0 + ko]);
            f32x4 v0 = src[0], v1 = src[1], v2 = src[2], v3 = src[3];
            short8 s0 = { f2bf(v0[0]), f2bf(v0[1]), f2bf(v0[2]), f2bf(v0[3]),
                          f2bf(v1[0]), f2bf(v1[1]), f2bf(v1[2]), f2bf(v1[3]) };
            short8 s1 = { f2bf(v2[0]), f2bf(v2[1]), f2bf(v2[2]), f2bf(v2[3]),
                          f2bf(v3[0]), f2bf(v3[1]), f2bf(v3[2]), f2bf(v3[3]) };
            *reinterpret_cast<short8*>(&Bt[r][ko])     = s0;
            *reinterpret_cast<short8*>(&Bt[r][ko + 8]) = s1;
        }
        __syncthreads();
        short8 af[4], bfr[2];
        #pragma unroll
        for (int fc = 0; fc < 4; ++fc)
            af[fc] = *reinterpret_cast<const short8*>(&At[fc * 16 + (lane & 15)][(lane >> 4) * 8]);
        #pragma unroll
        for (int fn = 0; fn < 2; ++fn)
            bfr[fn] = *reinterpret_cast<const short8*>(&Bt[wv * 32 + fn * 16 + (lane & 15)][(lane >> 4) * 8]);
        #pragma unroll
        for (int fc = 0; fc < 4; ++fc)
            #pragma unroll
            for (int fn = 0; fn < 2; ++fn)
                acc[fc][fn] = __builtin_amdgcn_mfma_f32_16x16x32_bf16(af[fc], bfr[fn], acc[fc][fn], 0, 0, 0);
    }

    int cg = lane >> 4, cl = lane & 15;
    #pragma unroll
    for (int fc = 0; fc < 4; ++fc)
        #pragma unroll
        for (int fn = 0; fn < 2; ++fn)
            #pragma unroll
            for (int reg = 0; reg < 4; ++reg) {
                int c = c0 + fc * 16 + cg * 4 + reg;
                int n = nb + wv * 32 + fn * 16 + cl;
                out[(size_t)b * ZSTRIDE + (size_t)c * NN + n] = acc[fc][fn][reg];
            }
}

extern "C" void kernel_launch(void* const* d_in, const int* in_sizes, int n_in,
                              void* d_out, int out_size, void* d_ws, size_t ws_size,
                              hipStream_t stream) {
    const float* z      = (const float*)d_in[0];
    const float* memory = (const float*)d_in[1];
    float* out      = (float*)d_out;
    float* out_attn = out + OUT_ATTN_OFF;

    char* wsb = (char*)d_ws;
    short* mem_h   = (short*)wsb;                     // 512*768*2 = 786432 B
    short* mem_m   = (short*)(wsb + 786432);
    short* mem_l   = (short*)(wsb + 1572864);
    short* memT_bf = (short*)(wsb + 2359296);         // total 3145728 B

    prep_mem_kernel<<<512, 256, 0, stream>>>(memory, mem_h, mem_m, mem_l, memT_bf);
    scores_attn_kernel<<<RR / 64, 256, 0, stream>>>(z, mem_h, mem_m, mem_l, out_attn);
    readout_kernel<<<dim3(CC / 64, RR / 128), 256, 0, stream>>>(memT_bf, out_attn, out);
}

// Round 6
// 331.477 us; speedup vs baseline: 1.5884x; 1.2116x over previous
//
#include <hip/hip_runtime.h>
#include <hip/hip_bf16.h>
#include <math.h>

typedef short short8 __attribute__((ext_vector_type(8)));
typedef float f32x4 __attribute__((ext_vector_type(4)));
typedef _Float16 f16x4 __attribute__((ext_vector_type(4)));
typedef _Float16 f16x8 __attribute__((ext_vector_type(8)));

#define CC 768
#define NN 1024
#define RR 32768
#define MM 512
#define ZSTRIDE 786432      // C*H*W
#define OUT_ATTN_OFF 25165824
#define SPLIT_SC 2048.0f
#define INV_SC   (1.0f / 2048.0f)

static __device__ __forceinline__ short f2bf(float f) {
    __hip_bfloat16 h = __float2bfloat16(f);
    return *reinterpret_cast<short*>(&h);
}

// fast exp for x in [-2.5, +1e-6], f64 accuracy ~1e-14 rel, branch-free
static __device__ __forceinline__ double fast_exp_neg(double x) {
    const double LOG2E = 1.4426950408889634074;
    const double LN2   = 0.6931471805599453094;
    const double MAGIC = 6755399441055744.0;     // 1.5 * 2^52
    double t = x * LOG2E;
    double c = t + MAGIC;
    double n = c - MAGIC;                         // rint(t)
    int ni = (int)__double2loint(c);
    double g = (t - n) * LN2;
    double r = 2.505210838544172e-08;
    r = fma(r, g, 2.755731922398589e-07);
    r = fma(r, g, 2.7557319223985893e-06);
    r = fma(r, g, 2.48015873015873e-05);
    r = fma(r, g, 1.984126984126984e-04);
    r = fma(r, g, 1.388888888888889e-03);
    r = fma(r, g, 8.333333333333333e-03);
    r = fma(r, g, 4.1666666666666664e-02);
    r = fma(r, g, 1.6666666666666666e-01);
    r = fma(r, g, 0.5);
    r = fma(r, g, 1.0);
    r = fma(r, g, 1.0);
    double sc = __hiloint2double((1023 + ni) << 20, 0);   // 2^n
    return r * sc;
}

static __device__ __forceinline__ double fast_rcp(double x) {
    double r = (double)(1.0f / (float)x);
    r = r * (2.0 - x * r);
    r = r * (2.0 - x * r);
    return r;
}

// ---------------- Kernel A: memory norms + f16 hi/lo split + raw bf16 transpose ----------
__global__ __launch_bounds__(256) void prep_mem_kernel(const float* __restrict__ memory,
                                                       _Float16* __restrict__ mem_h,
                                                       _Float16* __restrict__ mem_L,
                                                       short* __restrict__ memT_bf) {
    int m = blockIdx.x;      // 0..511
    int t = threadIdx.x;
    double ss = 0.0;
    for (int c = t; c < CC; c += 256) {
        float v = memory[m * CC + c];
        ss += (double)v * (double)v;
    }
    #pragma unroll
    for (int off = 32; off > 0; off >>= 1) ss += __shfl_xor(ss, off);
    __shared__ double red[4];
    __shared__ double invs;
    if ((t & 63) == 0) red[t >> 6] = ss;
    __syncthreads();
    if (t == 0) {
        double tot = red[0] + red[1] + red[2] + red[3];
        invs = 1.0 / fmax(sqrt(tot), 1e-12);
    }
    __syncthreads();
    float inv = (float)invs;
    for (int c = t; c < CC; c += 256) {
        float v  = memory[m * CC + c];
        float nv = v * inv;
        _Float16 h = (_Float16)nv;
        float r1 = nv - (float)h;
        mem_h[m * CC + c] = h;
        mem_L[m * CC + c] = (_Float16)(r1 * SPLIT_SC);
        memT_bf[c * MM + m] = f2bf(v);
    }
}

// ---------------- Kernel B (pass 1): raw scores GEMM via f16 2-split MFMA --------------
// Block: 32 z-rows x 256 cols, 256 threads = 4 waves. Wave wv = 32 rows x 64 cols.
// acc[fc][fn]: D row = fc*16 + (lane>>4)*4 + reg, D col = c0 + fn*16 + (lane&15).
__global__ __launch_bounds__(256, 3) void scores_gemm_kernel(const float* __restrict__ z,
                                                             const _Float16* __restrict__ mem_h,
                                                             const _Float16* __restrict__ mem_L,
                                                             float* __restrict__ out_scores,
                                                             double* __restrict__ zinv_ws) {
    __shared__ _Float16 AT[2][2][32][40];   // [buf][h/L][row][k padded] = 10 KB
    __shared__ double ssred[256];

    const int t    = threadIdx.x;
    const int lane = t & 63;
    const int wv   = t >> 6;
    const int lrow = lane & 15;
    const int gk   = lane >> 4;
    const int rowblk = blockIdx.x;           // 0..1023
    const int colblk = blockIdx.y;           // 0..1
    const int row0 = rowblk * 32;
    const int b    = row0 >> 10;
    const int n0   = row0 & 1023;
    const int c0   = colblk * 256 + wv * 64;
    const float* zbase = z + (size_t)b * ZSTRIDE + n0;

    const int sn = t & 31;            // staging row (n)
    const int sk = (t >> 5) * 4;      // staging k base

    double ss = 0.0;
    f32x4 am[2][4], ax[2][4];
    #pragma unroll
    for (int fc = 0; fc < 2; ++fc)
        #pragma unroll
        for (int fn = 0; fn < 4; ++fn) {
            am[fc][fn] = (f32x4){0.f, 0.f, 0.f, 0.f};
            ax[fc][fn] = (f32x4){0.f, 0.f, 0.f, 0.f};
        }

    // ---- prologue: stage tile 0 ----
    {
        float v[4];
        #pragma unroll
        for (int j = 0; j < 4; ++j) v[j] = zbase[(size_t)(sk + j) * NN + sn];
        f16x4 h4, l4;
        #pragma unroll
        for (int j = 0; j < 4; ++j) {
            ss = fma((double)v[j], (double)v[j], ss);
            _Float16 h = (_Float16)v[j];
            h4[j] = h;
            l4[j] = (_Float16)((v[j] - (float)h) * SPLIT_SC);
        }
        *reinterpret_cast<f16x4*>(&AT[0][0][sn][sk]) = h4;
        *reinterpret_cast<f16x4*>(&AT[0][1][sn][sk]) = l4;
    }
    __syncthreads();

    #pragma unroll 1
    for (int kt = 0; kt < 24; ++kt) {
        const int cur = kt & 1;
        const bool dostage = (kt < 23);
        // T14: issue next tile's z loads early
        float v[4];
        if (dostage) {
            #pragma unroll
            for (int j = 0; j < 4; ++j)
                v[j] = zbase[(size_t)((kt + 1) * 32 + sk + j) * NN + sn];
        }
        // fragments
        f16x8 ah[2], aL[2];
        #pragma unroll
        for (int fc = 0; fc < 2; ++fc) {
            ah[fc] = *reinterpret_cast<const f16x8*>(&AT[cur][0][fc * 16 + lrow][gk * 8]);
            aL[fc] = *reinterpret_cast<const f16x8*>(&AT[cur][1][fc * 16 + lrow][gk * 8]);
        }
        f16x8 bh[4], bL[4];
        #pragma unroll
        for (int fn = 0; fn < 4; ++fn) {
            const size_t moff = (size_t)(c0 + fn * 16 + lrow) * CC + kt * 32 + gk * 8;
            bh[fn] = *reinterpret_cast<const f16x8*>(mem_h + moff);
            bL[fn] = *reinterpret_cast<const f16x8*>(mem_L + moff);
        }
        #pragma unroll
        for (int fn = 0; fn < 4; ++fn)
            #pragma unroll
            for (int fc = 0; fc < 2; ++fc) {
                am[fc][fn] = __builtin_amdgcn_mfma_f32_16x16x32_f16(ah[fc], bh[fn], am[fc][fn], 0, 0, 0);
                ax[fc][fn] = __builtin_amdgcn_mfma_f32_16x16x32_f16(aL[fc], bh[fn], ax[fc][fn], 0, 0, 0);
                ax[fc][fn] = __builtin_amdgcn_mfma_f32_16x16x32_f16(ah[fc], bL[fn], ax[fc][fn], 0, 0, 0);
            }
        // write-late: convert + ds_write for next tile
        if (dostage) {
            f16x4 h4, l4;
            #pragma unroll
            for (int j = 0; j < 4; ++j) {
                ss = fma((double)v[j], (double)v[j], ss);
                _Float16 h = (_Float16)v[j];
                h4[j] = h;
                l4[j] = (_Float16)((v[j] - (float)h) * SPLIT_SC);
            }
            *reinterpret_cast<f16x4*>(&AT[cur ^ 1][0][sn][sk]) = h4;
            *reinterpret_cast<f16x4*>(&AT[cur ^ 1][1][sn][sk]) = l4;
        }
        __syncthreads();
    }

    // ---- store raw scores (f32) ----
    #pragma unroll
    for (int fc = 0; fc < 2; ++fc)
        #pragma unroll
        for (int fn = 0; fn < 4; ++fn)
            #pragma unroll
            for (int reg = 0; reg < 4; ++reg) {
                int row = row0 + fc * 16 + gk * 4 + reg;
                int col = c0 + fn * 16 + lrow;
                out_scores[(size_t)row * MM + col] = am[fc][fn][reg] + ax[fc][fn][reg] * INV_SC;
            }

    // ---- row inverse norms (colblk 0 only writes) ----
    ssred[t] = ss;
    __syncthreads();
    if (colblk == 0 && t < 32) {
        double tot = 0.0;
        #pragma unroll
        for (int g = 0; g < 8; ++g) tot += ssred[g * 32 + t];
        zinv_ws[row0 + t] = 1.0 / fmax(sqrt(tot), 1e-12);
    }
}

// ---------------- Kernel C (pass 2): in-place softmax + hardshrink + renorm (f64) -------
// Block: 64 rows, 256 threads = 4 waves; wave handles 16 rows, row spans the wave.
// Lane holds cols {lane*4+j, 256+lane*4+j}.
__global__ __launch_bounds__(256) void epilogue_kernel(float* __restrict__ attn,
                                                       const double* __restrict__ zinv_ws) {
    const int t    = threadIdx.x;
    const int lane = t & 63;
    const int wv   = t >> 6;
    const int row0 = blockIdx.x * 64;

    #pragma unroll 1
    for (int i = 0; i < 16; ++i) {
        int row = row0 + wv * 16 + i;
        double zi = zinv_ws[row];
        float* rp = attn + (size_t)row * MM;
        f32x4 x0 = *reinterpret_cast<const f32x4*>(&rp[lane * 4]);
        f32x4 x1 = *reinterpret_cast<const f32x4*>(&rp[256 + lane * 4]);
        double s0 = (double)x0[0] * zi, s1 = (double)x0[1] * zi;
        double s2 = (double)x0[2] * zi, s3 = (double)x0[3] * zi;
        double s4 = (double)x1[0] * zi, s5 = (double)x1[1] * zi;
        double s6 = (double)x1[2] * zi, s7 = (double)x1[3] * zi;
        double mx = fmax(fmax(fmax(s0, s1), fmax(s2, s3)),
                         fmax(fmax(s4, s5), fmax(s6, s7)));
        #pragma unroll
        for (int off = 32; off > 0; off >>= 1) mx = fmax(mx, __shfl_xor(mx, off));
        double p0 = fast_exp_neg(s0 - mx), p1 = fast_exp_neg(s1 - mx);
        double p2 = fast_exp_neg(s2 - mx), p3 = fast_exp_neg(s3 - mx);
        double p4 = fast_exp_neg(s4 - mx), p5 = fast_exp_neg(s5 - mx);
        double p6 = fast_exp_neg(s6 - mx), p7 = fast_exp_neg(s7 - mx);
        double Z = ((p0 + p1) + (p2 + p3)) + ((p4 + p5) + (p6 + p7));
        #pragma unroll
        for (int off = 32; off > 0; off >>= 1) Z += __shfl_xor(Z, off);
        double iZ = fast_rcp(Z);
        const double LAM = 1.0 / 512.0;
        double w0 = p0 * iZ, w1 = p1 * iZ, w2 = p2 * iZ, w3 = p3 * iZ;
        double w4 = p4 * iZ, w5 = p5 * iZ, w6 = p6 * iZ, w7 = p7 * iZ;
        double d0 = w0 - LAM, d1 = w1 - LAM, d2 = w2 - LAM, d3 = w3 - LAM;
        double d4 = w4 - LAM, d5 = w5 - LAM, d6 = w6 - LAM, d7 = w7 - LAM;
        double e0 = (d0 > 0.0 ? d0 : 0.0) * w0 * fast_rcp(fabs(d0) + 1e-8);
        double e1 = (d1 > 0.0 ? d1 : 0.0) * w1 * fast_rcp(fabs(d1) + 1e-8);
        double e2 = (d2 > 0.0 ? d2 : 0.0) * w2 * fast_rcp(fabs(d2) + 1e-8);
        double e3 = (d3 > 0.0 ? d3 : 0.0) * w3 * fast_rcp(fabs(d3) + 1e-8);
        double e4 = (d4 > 0.0 ? d4 : 0.0) * w4 * fast_rcp(fabs(d4) + 1e-8);
        double e5 = (d5 > 0.0 ? d5 : 0.0) * w5 * fast_rcp(fabs(d5) + 1e-8);
        double e6 = (d6 > 0.0 ? d6 : 0.0) * w6 * fast_rcp(fabs(d6) + 1e-8);
        double e7 = (d7 > 0.0 ? d7 : 0.0) * w7 * fast_rcp(fabs(d7) + 1e-8);
        double S = ((e0 + e1) + (e2 + e3)) + ((e4 + e5) + (e6 + e7));
        #pragma unroll
        for (int off = 32; off > 0; off >>= 1) S += __shfl_xor(S, off);
        double rinv = fast_rcp(S + 1e-8);
        f32x4 o0 = { (float)(e0 * rinv), (float)(e1 * rinv),
                     (float)(e2 * rinv), (float)(e3 * rinv) };
        f32x4 o1 = { (float)(e4 * rinv), (float)(e5 * rinv),
                     (float)(e6 * rinv), (float)(e7 * rinv) };
        *reinterpret_cast<f32x4*>(&rp[lane * 4])       = o0;
        *reinterpret_cast<f32x4*>(&rp[256 + lane * 4]) = o1;
    }
}

// ---------------- Kernel D: z_hat = attn @ memory via bf16 MFMA ----------------
__global__ __launch_bounds__(256) void readout_kernel(const short* __restrict__ memT_bf,
                                                      const float* __restrict__ attn,
                                                      float* __restrict__ out) {
    __shared__ short At[64][40];    // 64 c-rows x 32 k, padded
    __shared__ short Bt[128][40];   // 128 n-rows x 32 k
    int t = threadIdx.x;
    int c0     = blockIdx.x * 64;
    int rowblk = blockIdx.y * 128;
    int b  = rowblk >> 10;
    int nb = rowblk & 1023;
    int lane = t & 63, wv = t >> 6;

    f32x4 acc[4][2];
    #pragma unroll
    for (int fc = 0; fc < 4; ++fc)
        #pragma unroll
        for (int fn = 0; fn < 2; ++fn) acc[fc][fn] = (f32x4){0.f, 0.f, 0.f, 0.f};

    for (int m0 = 0; m0 < MM; m0 += 32) {
        __syncthreads();
        {   // stage A: 64 x 32 bf16
            int r = t >> 2, ko = (t & 3) * 8;
            short8 v = *reinterpret_cast<const short8*>(&memT_bf[(c0 + r) * MM + m0 + ko]);
            *reinterpret_cast<short8*>(&At[r][ko]) = v;
        }
        {   // stage B: 128 x 32, attn f32 -> bf16, vectorized
            int r = t >> 1, ko = (t & 1) * 16;
            const f32x4* src = reinterpret_cast<const f32x4*>(
                &attn[(size_t)(rowblk + r) * MM + m0 + ko]);
            f32x4 v0 = src[0], v1 = src[1], v2 = src[2], v3 = src[3];
            short8 s0 = { f2bf(v0[0]), f2bf(v0[1]), f2bf(v0[2]), f2bf(v0[3]),
                          f2bf(v1[0]), f2bf(v1[1]), f2bf(v1[2]), f2bf(v1[3]) };
            short8 s1 = { f2bf(v2[0]), f2bf(v2[1]), f2bf(v2[2]), f2bf(v2[3]),
                          f2bf(v3[0]), f2bf(v3[1]), f2bf(v3[2]), f2bf(v3[3]) };
            *reinterpret_cast<short8*>(&Bt[r][ko])     = s0;
            *reinterpret_cast<short8*>(&Bt[r][ko + 8]) = s1;
        }
        __syncthreads();
        short8 af[4], bfr[2];
        #pragma unroll
        for (int fc = 0; fc < 4; ++fc)
            af[fc] = *reinterpret_cast<const short8*>(&At[fc * 16 + (lane & 15)][(lane >> 4) * 8]);
        #pragma unroll
        for (int fn = 0; fn < 2; ++fn)
            bfr[fn] = *reinterpret_cast<const short8*>(&Bt[wv * 32 + fn * 16 + (lane & 15)][(lane >> 4) * 8]);
        #pragma unroll
        for (int fc = 0; fc < 4; ++fc)
            #pragma unroll
            for (int fn = 0; fn < 2; ++fn)
                acc[fc][fn] = __builtin_amdgcn_mfma_f32_16x16x32_bf16(af[fc], bfr[fn], acc[fc][fn], 0, 0, 0);
    }

    int cg = lane >> 4, cl = lane & 15;
    #pragma unroll
    for (int fc = 0; fc < 4; ++fc)
        #pragma unroll
        for (int fn = 0; fn < 2; ++fn)
            #pragma unroll
            for (int reg = 0; reg < 4; ++reg) {
                int c = c0 + fc * 16 + cg * 4 + reg;
                int n = nb + wv * 32 + fn * 16 + cl;
                out[(size_t)b * ZSTRIDE + (size_t)c * NN + n] = acc[fc][fn][reg];
            }
}

extern "C" void kernel_launch(void* const* d_in, const int* in_sizes, int n_in,
                              void* d_out, int out_size, void* d_ws, size_t ws_size,
                              hipStream_t stream) {
    const float* z      = (const float*)d_in[0];
    const float* memory = (const float*)d_in[1];
    float* out      = (float*)d_out;
    float* out_attn = out + OUT_ATTN_OFF;

    char* wsb = (char*)d_ws;
    _Float16* mem_h   = (_Float16*)wsb;               // 512*768*2 = 786432 B
    _Float16* mem_L   = (_Float16*)(wsb + 786432);
    short*    memT_bf = (short*)(wsb + 1572864);
    double*   zinv_ws = (double*)(wsb + 2359296);     // 32768*8 = 262144 B

    prep_mem_kernel<<<512, 256, 0, stream>>>(memory, mem_h, mem_L, memT_bf);
    scores_gemm_kernel<<<dim3(RR / 32, 2), 256, 0, stream>>>(z, mem_h, mem_L, out_attn, zinv_ws);
    epilogue_kernel<<<RR / 64, 256, 0, stream>>>(out_attn, zinv_ws);
    readout_kernel<<<dim3(CC / 64, RR / 128), 256, 0, stream>>>(memT_bf, out_attn, out);
}